// Round 6
// baseline (363.148 us; speedup 1.0000x reference)
//
#include <hip/hip_runtime.h>
#include <math.h>

// MoE router: T=16384 tokens, H=4096, E=8 experts, K=2.
// d_out layout (float32, flat, reference return order):
//   [0      , 32768 )  routing_weights  (T,2)
//   [32768  , 65536 )  selected_experts (T,2)  stored as float(index)
//   [65536  , 196608)  router_logits    (T,8)
//   [196608 ]          aux_loss (scalar)
// d_ws: 16 rows x NBLOCKS of per-block partials (plain stores, no init).
//
// R6 change: maximum TLP, minimum cleverness. R0/R3/R5 (no-pipeline, reg
// depth-1, counted-vmcnt LDS ring) ALL land at 75-82us ~ 3.2 TB/s — the
// shared invariant is <=16 waves/CU. The 6.3 TB/s copy ubench reads the same
// 1KB-per-instruction runs but at ~32 waves/CU with no per-iteration waits.
// So: TOK_PER_WAVE 2, grid 2048 (8 blocks/CU), live set ~50 VGPR (acc 16 +
// hv 8 + gate-half 16 + addr), launch_bounds(256,8) -> 8 waves/SIMD =
// 32 waves/CU. No LDS ring, no asm waits: waves stall naturally, 8-deep
// round-robin hides it (per-iter VALU ~300cy x 8 waves >= 900cy HBM lat).
// Gate loaded in two 4-expert halves to keep peak pressure ~50 (cap 64 with
// 25% slack — not an R2-style squeeze). Gate L2 traffic doubles to 1 GB
// (~22 TB/s demand, 64% of L2 aggregate — acceptable). NT on hidden keeps
// the 256 MB stream from evicting the L2-resident gate.

#define T_TOKENS 16384
#define H_DIM    4096
#define NEXP     8
#define H4       (H_DIM / 4)   // 1024 float4 per row
#define ITERS    (H4 / 64)     // 16 float4 chunks per lane per token
#define TOK_PER_WAVE 2
#define WAVES_PER_BLOCK 4
#define TOK_PER_BLOCK (TOK_PER_WAVE * WAVES_PER_BLOCK)  // 8
#define NBLOCKS (T_TOKENS / TOK_PER_BLOCK)              // 2048

#define OFF_RW  0
#define OFF_SE  32768
#define OFF_LG  65536
#define OFF_AUX 196608

// Native vector type usable with __builtin_nontemporal_load (HIP's float4 is
// a class and is rejected by the builtin).
typedef float vfloat4 __attribute__((ext_vector_type(4)));

// Halving butterfly step: value set of size 2N -> N, summing over lane pairs
// differing in bit OFFSET. See epilogue for the value->lane mapping.
#define RED_STEP(OFFSET, N)                                        \
  {                                                                \
    const bool hi = (lane & (OFFSET)) != 0;                        \
    _Pragma("unroll")                                              \
    for (int i = 0; i < (N); ++i) {                                \
      float send = hi ? r[i] : r[i + (N)];                         \
      float recv = __shfl_xor(send, (OFFSET), 64);                 \
      r[i] = (hi ? r[i + (N)] : r[i]) + recv;                      \
    }                                                              \
  }

__global__ __launch_bounds__(256, 8)
void router_kernel(const float* __restrict__ hs, const float* __restrict__ gw,
                   float* __restrict__ out, float* __restrict__ ws) {
  __shared__ float smP[NEXP];
  __shared__ float smC[NEXP];
  if (threadIdx.x < NEXP) { smP[threadIdx.x] = 0.f; smC[threadIdx.x] = 0.f; }
  __syncthreads();

  const int lane = threadIdx.x & 63;
  const int wave = threadIdx.x >> 6;
  const int tokenBase = (blockIdx.x * WAVES_PER_BLOCK + wave) * TOK_PER_WAVE;

  const vfloat4* __restrict__ h4p = reinterpret_cast<const vfloat4*>(hs);
  const vfloat4* __restrict__ g4p = reinterpret_cast<const vfloat4*>(gw);

  float r[TOK_PER_WAVE * NEXP];  // 16 accumulators: r[t*8+e]
#pragma unroll
  for (int i = 0; i < TOK_PER_WAVE * NEXP; ++i) r[i] = 0.f;

  for (int k = 0; k < ITERS; ++k) {
    const int idx = lane + 64 * k;
    // Hidden: 2 NT float4 loads (read-once 256 MB stream, keep out of L2).
    vfloat4 hv0 = __builtin_nontemporal_load(&h4p[(tokenBase + 0) * H4 + idx]);
    vfloat4 hv1 = __builtin_nontemporal_load(&h4p[(tokenBase + 1) * H4 + idx]);
    // Gate in two 4-expert halves: peak live regs ~50 (acc16+hv8+g16+addr),
    // comfortably under the 64-VGPR cap of launch_bounds(256,8).
#pragma unroll
    for (int half = 0; half < 2; ++half) {
      vfloat4 g[4];
#pragma unroll
      for (int e = 0; e < 4; ++e) g[e] = g4p[(half * 4 + e) * H4 + idx];
#pragma unroll
      for (int e = 0; e < 4; ++e) {
        const int ei = half * 4 + e;
        float a0 = r[0 * NEXP + ei];
        float a1 = r[1 * NEXP + ei];
        a0 = fmaf(hv0.x, g[e].x, a0); a1 = fmaf(hv1.x, g[e].x, a1);
        a0 = fmaf(hv0.y, g[e].y, a0); a1 = fmaf(hv1.y, g[e].y, a1);
        a0 = fmaf(hv0.z, g[e].z, a0); a1 = fmaf(hv1.z, g[e].z, a1);
        a0 = fmaf(hv0.w, g[e].w, a0); a1 = fmaf(hv1.w, g[e].w, a1);
        r[0 * NEXP + ei] = a0;
        r[1 * NEXP + ei] = a1;
      }
    }
  }

  // Reduce 16 values over 64 lanes. Halving butterfly over xor distances
  // 32,16,8,4 (value index v picks up bits: v = (lane>>2)&15 afterward),
  // then two plain allreduce folds over xor 2,1 complete the 64-lane sum.
  // Result: every lane holds the full sum of value v=(lane>>2)&15, where
  // v = t*8+e (t = v>>3 in {0,1}, e = v&7).
  RED_STEP(32, 8)
  RED_STEP(16, 4)
  RED_STEP(8, 2)
  float red;
  {
    const bool hi = (lane & 4) != 0;
    float send = hi ? r[0] : r[1];
    float recv = __shfl_xor(send, 4, 64);
    red = (hi ? r[1] : r[0]) + recv;
  }
  red += __shfl_xor(red, 2, 64);
  red += __shfl_xor(red, 1, 64);

  // One lane per value stores its logit: 64 B contiguous per wave.
  if ((lane & 3) == 0) out[OFF_LG + tokenBase * NEXP + (lane >> 2)] = red;

  // Gather the 8 logits of this half-wave's token: token t = lane>>5,
  // logit e lives in lane (t<<5) + (e<<2).
  float le[NEXP];
#pragma unroll
  for (int e = 0; e < NEXP; ++e) le[e] = __shfl(red, (lane & 32) + (e << 2), 64);

  if ((lane & 31) == 0) {
    const int tok = tokenBase + (lane >> 5);
    // top-1 (strict > => lowest index wins ties, like lax.top_k)
    int i1 = 0; float m1 = le[0];
#pragma unroll
    for (int e = 1; e < NEXP; ++e) {
      if (le[e] > m1) { m1 = le[e]; i1 = e; }
    }
    int i2 = (i1 == 0) ? 1 : 0; float m2 = le[i2];
#pragma unroll
    for (int e = 0; e < NEXP; ++e) {
      if (e != i1 && le[e] > m2) { m2 = le[e]; i2 = e; }
    }
    // full softmax (max-shifted)
    float p[NEXP];
    float psum = 0.f;
#pragma unroll
    for (int e = 0; e < NEXP; ++e) { p[e] = expf(le[e] - m1); psum += p[e]; }
    const float inv = 1.0f / psum;
#pragma unroll
    for (int e = 0; e < NEXP; ++e) atomicAdd(&smP[e], p[e] * inv);
    atomicAdd(&smC[i1], 1.0f);

    // normalized top-2 routing weights: p[i1] = 1, p[i2] = exp(m2-m1)
    const float w1 = p[i1], w2 = p[i2];
    const float rs = 1.0f / (w1 + w2);
    out[OFF_RW + tok * 2 + 0] = w1 * rs;
    out[OFF_RW + tok * 2 + 1] = w2 * rs;
    out[OFF_SE + tok * 2 + 0] = (float)i1;
    out[OFF_SE + tok * 2 + 1] = (float)i2;
  }

  __syncthreads();
  // Per-block partials: row-major [16 rows][NBLOCKS]; plain stores, no
  // init needed (d_ws is poison — we overwrite every slot we later read).
  if (threadIdx.x < 2 * NEXP) {
    const float v = (threadIdx.x < NEXP) ? smP[threadIdx.x]
                                         : smC[threadIdx.x - NEXP];
    ws[threadIdx.x * NBLOCKS + blockIdx.x] = v;
  }
}

__global__ __launch_bounds__(1024)
void aux_kernel(const float* __restrict__ ws, float* __restrict__ out) {
  __shared__ float sm[2 * NEXP];
  const int lane = threadIdx.x & 63;
  const int w = threadIdx.x >> 6;  // 16 waves, one per partial row
  float s = 0.f;
#pragma unroll
  for (int i = 0; i < NBLOCKS / 64; ++i) s += ws[w * NBLOCKS + lane + 64 * i];
#pragma unroll
  for (int off = 32; off > 0; off >>= 1) s += __shfl_xor(s, off, 64);
  if (lane == 0) sm[w] = s;
  __syncthreads();
  if (threadIdx.x == 0) {
    const float invT = 1.0f / (float)T_TOKENS;
    float acc = 0.f;
#pragma unroll
    for (int e = 0; e < NEXP; ++e) {
      const float f = sm[NEXP + e] * invT;  // mean one-hot(top1)
      const float P = sm[e] * invT;         // mean probs
      acc += f * P;
    }
    out[OFF_AUX] = 0.01f * (float)NEXP * acc;
  }
}

extern "C" void kernel_launch(void* const* d_in, const int* in_sizes, int n_in,
                              void* d_out, int out_size, void* d_ws, size_t ws_size,
                              hipStream_t stream) {
  const float* hs = (const float*)d_in[0];   // (16384, 4096) f32
  const float* gw = (const float*)d_in[1];   // (8, 4096) f32
  float* out = (float*)d_out;
  float* ws  = (float*)d_ws;

  router_kernel<<<NBLOCKS, 256, 0, stream>>>(hs, gw, out, ws);
  aux_kernel<<<1, 1024, 0, stream>>>(ws, out);
}

// Round 7
// 353.199 us; speedup vs baseline: 1.0282x; 1.0282x over previous
//
#include <hip/hip_runtime.h>
#include <math.h>

// MoE router: T=16384 tokens, H=4096, E=8 experts, K=2.
// d_out layout (float32, flat, reference return order):
//   [0      , 32768 )  routing_weights  (T,2)
//   [32768  , 65536 )  selected_experts (T,2)  stored as float(index)
//   [65536  , 196608)  router_logits    (T,8)
//   [196608 ]          aux_loss (scalar)
// d_ws: 16 rows x NBLOCKS of per-block partials (plain stores, no init):
//   row e   (e=0..7):  sum of softmax probs for expert e
//   row 8+e (e=0..7):  top-1 counts for expert e
//
// R7: revert to the verified-best R3 kernel (353.6 us total, router ~75 us).
// Experiment matrix R0-R6 (no-pipeline / reg-dbuf / LDS-gate / async
// global_load_lds ring with counted vmcnt / 32-waves-per-CU max-TLP) ALL
// converge at 3.2-3.4 TB/s read BW. Model: the read path on this part
// saturates at ~3.4 TB/s; the 6.3 TB/s "achievable" figure is read+write
// combined (fills hit 6.5 write-only; copy ubench = 3.15 read + 3.15 write).
// This kernel reads 268 MB / writes ~1 MB -> floor = 268/3.4 ~ 79 us =
// what this kernel delivers. At roofline; structure below is the simplest
// design that reaches it: depth-1 register prefetch on the NT hidden
// stream, gate direct from L2, 16 waves/CU, ~106 VGPR (no spill).

#define T_TOKENS 16384
#define H_DIM    4096
#define NEXP     8
#define H4       (H_DIM / 4)   // 1024 float4 per row
#define ITERS    (H4 / 64)     // 16 float4 chunks per lane per token
#define TOK_PER_WAVE 4
#define WAVES_PER_BLOCK 4
#define TOK_PER_BLOCK (TOK_PER_WAVE * WAVES_PER_BLOCK)  // 16
#define NBLOCKS (T_TOKENS / TOK_PER_BLOCK)              // 1024

#define OFF_RW  0
#define OFF_SE  32768
#define OFF_LG  65536
#define OFF_AUX 196608

// Native vector type usable with __builtin_nontemporal_load (HIP's float4 is
// a class and is rejected by the builtin).
typedef float vfloat4 __attribute__((ext_vector_type(4)));

// Halving butterfly step: value set of size 2N -> N, summing over lane pairs
// differing in bit OFFSET. Starting from 32 values r[0..31] and steps
// OFFSET=16,8,4,2,1, lane l ends holding the 32-lane-half sum of value (l&31).
#define RED_STEP(OFFSET, N)                                        \
  {                                                                \
    const bool hi = (lane & (OFFSET)) != 0;                        \
    _Pragma("unroll")                                              \
    for (int i = 0; i < (N); ++i) {                                \
      float send = hi ? r[i] : r[i + (N)];                         \
      float recv = __shfl_xor(send, (OFFSET), 64);                 \
      r[i] = (hi ? r[i + (N)] : r[i]) + recv;                      \
    }                                                              \
  }

// Issue the 4 hidden NT loads for chunk KIDX into a named register buffer.
#define LOAD_H(HV, KIDX)                                           \
  {                                                                \
    const int idx_ = lane + 64 * (KIDX);                           \
    _Pragma("unroll")                                              \
    for (int t = 0; t < TOK_PER_WAVE; ++t)                         \
      HV[t] = __builtin_nontemporal_load(                          \
          &h4p[(tokenBase + t) * H4 + idx_]);                      \
  }

// Load this chunk's 8 gate float4s (L1/L2-warm) and do the 128 FMAs.
#define GATE_AND_COMPUTE(HV, KIDX)                                 \
  {                                                                \
    const int idx_ = lane + 64 * (KIDX);                           \
    vfloat4 g[NEXP];                                               \
    _Pragma("unroll")                                              \
    for (int e = 0; e < NEXP; ++e) g[e] = g4p[e * H4 + idx_];      \
    _Pragma("unroll")                                              \
    for (int t = 0; t < TOK_PER_WAVE; ++t) {                       \
      _Pragma("unroll")                                            \
      for (int e = 0; e < NEXP; ++e) {                             \
        float a = r[t * NEXP + e];                                 \
        a = fmaf(HV[t].x, g[e].x, a);                              \
        a = fmaf(HV[t].y, g[e].y, a);                              \
        a = fmaf(HV[t].z, g[e].z, a);                              \
        a = fmaf(HV[t].w, g[e].w, a);                              \
        r[t * NEXP + e] = a;                                       \
      }                                                            \
    }                                                              \
  }

__global__ __launch_bounds__(256, 2)
void router_kernel(const float* __restrict__ hs, const float* __restrict__ gw,
                   float* __restrict__ out, float* __restrict__ ws) {
  __shared__ float smP[NEXP];
  __shared__ float smC[NEXP];
  if (threadIdx.x < NEXP) { smP[threadIdx.x] = 0.f; smC[threadIdx.x] = 0.f; }
  __syncthreads();

  const int lane = threadIdx.x & 63;
  const int wave = threadIdx.x >> 6;
  const int tokenBase = (blockIdx.x * WAVES_PER_BLOCK + wave) * TOK_PER_WAVE;

  const vfloat4* __restrict__ h4p = reinterpret_cast<const vfloat4*>(hs);
  const vfloat4* __restrict__ g4p = reinterpret_cast<const vfloat4*>(gw);

  float r[TOK_PER_WAVE * NEXP];  // 32 accumulators: r[t*8+e]
#pragma unroll
  for (int i = 0; i < TOK_PER_WAVE * NEXP; ++i) r[i] = 0.f;

  // Depth-1 pipeline on the HIDDEN stream only. Named A/B buffers with a
  // k+=2 loop: every register access is compile-time-indexed. Gate is
  // loaded inside each compute step (cache-warm, short latency).
  vfloat4 hvA[TOK_PER_WAVE], hvB[TOK_PER_WAVE];

  LOAD_H(hvA, 0)
  for (int k = 0; k < ITERS; k += 2) {
    LOAD_H(hvB, k + 1)              // prefetch odd hidden chunk
    GATE_AND_COMPUTE(hvA, k)        // consume even chunk (loaded last iter)
    if (k + 2 < ITERS) {
      LOAD_H(hvA, k + 2)            // prefetch next even hidden chunk
    }
    GATE_AND_COMPUTE(hvB, k + 1)    // consume odd chunk
  }

  // 32-value butterfly within each 32-lane half: lane l ends holding the
  // half-sum of value (l&31) (token = (l&31)>>3, expert = l&7).
  RED_STEP(16, 16)
  RED_STEP(8, 8)
  RED_STEP(4, 4)
  RED_STEP(2, 2)
  float red;
  {
    const bool hi = (lane & 1) != 0;
    float send = hi ? r[0] : r[1];
    float recv = __shfl_xor(send, 1, 64);
    red = (hi ? r[1] : r[0]) + recv;
  }
  // Fold the two 32-lane halves: every lane now holds the full 64-lane sum
  // of value (lane&31).
  red += __shfl_xor(red, 32, 64);

  // Lanes 0..31 store one logit each: 128 B contiguous per wave.
  if (lane < 32) out[OFF_LG + tokenBase * NEXP + lane] = red;

  // Gather the 8 logits of this lane-group's token (source lanes 0..31 hold
  // full sums; all 64 lanes execute the shfl).
  float le[NEXP];
  const int groupBase = lane & 24;
#pragma unroll
  for (int e = 0; e < NEXP; ++e) le[e] = __shfl(red, groupBase + e, 64);

  if (lane < 32 && (lane & 7) == 0) {
    const int tok = tokenBase + (lane >> 3);
    // top-1 (strict > => lowest index wins ties, like lax.top_k)
    int i1 = 0; float m1 = le[0];
#pragma unroll
    for (int e = 1; e < NEXP; ++e) {
      if (le[e] > m1) { m1 = le[e]; i1 = e; }
    }
    int i2 = (i1 == 0) ? 1 : 0; float m2 = le[i2];
#pragma unroll
    for (int e = 0; e < NEXP; ++e) {
      if (e != i1 && le[e] > m2) { m2 = le[e]; i2 = e; }
    }
    // full softmax (max-shifted)
    float p[NEXP];
    float psum = 0.f;
#pragma unroll
    for (int e = 0; e < NEXP; ++e) { p[e] = expf(le[e] - m1); psum += p[e]; }
    const float inv = 1.0f / psum;
#pragma unroll
    for (int e = 0; e < NEXP; ++e) atomicAdd(&smP[e], p[e] * inv);
    atomicAdd(&smC[i1], 1.0f);

    // normalized top-2 routing weights: p[i1] = 1, p[i2] = exp(m2-m1)
    const float w1 = p[i1], w2 = p[i2];
    const float rs = 1.0f / (w1 + w2);
    out[OFF_RW + tok * 2 + 0] = w1 * rs;
    out[OFF_RW + tok * 2 + 1] = w2 * rs;
    out[OFF_SE + tok * 2 + 0] = (float)i1;
    out[OFF_SE + tok * 2 + 1] = (float)i2;
  }

  __syncthreads();
  // Per-block partials: row-major [16 rows][NBLOCKS]; plain stores, no
  // init needed (d_ws is poison — we overwrite every slot we later read).
  if (threadIdx.x < 2 * NEXP) {
    const float v = (threadIdx.x < NEXP) ? smP[threadIdx.x]
                                         : smC[threadIdx.x - NEXP];
    ws[threadIdx.x * NBLOCKS + blockIdx.x] = v;
  }
}

__global__ __launch_bounds__(1024)
void aux_kernel(const float* __restrict__ ws, float* __restrict__ out) {
  __shared__ float sm[2 * NEXP];
  const int lane = threadIdx.x & 63;
  const int w = threadIdx.x >> 6;  // 16 waves, one per partial row
  float s = 0.f;
#pragma unroll
  for (int i = 0; i < NBLOCKS / 64; ++i) s += ws[w * NBLOCKS + lane + 64 * i];
#pragma unroll
  for (int off = 32; off > 0; off >>= 1) s += __shfl_xor(s, off, 64);
  if (lane == 0) sm[w] = s;
  __syncthreads();
  if (threadIdx.x == 0) {
    const float invT = 1.0f / (float)T_TOKENS;
    float acc = 0.f;
#pragma unroll
    for (int e = 0; e < NEXP; ++e) {
      const float f = sm[NEXP + e] * invT;  // mean one-hot(top1)
      const float P = sm[e] * invT;         // mean probs
      acc += f * P;
    }
    out[OFF_AUX] = 0.01f * (float)NEXP * acc;
  }
}

extern "C" void kernel_launch(void* const* d_in, const int* in_sizes, int n_in,
                              void* d_out, int out_size, void* d_ws, size_t ws_size,
                              hipStream_t stream) {
  const float* hs = (const float*)d_in[0];   // (16384, 4096) f32
  const float* gw = (const float*)d_in[1];   // (8, 4096) f32
  float* out = (float*)d_out;
  float* ws  = (float*)d_ws;

  router_kernel<<<NBLOCKS, 256, 0, stream>>>(hs, gw, out, ws);
  aux_kernel<<<1, 1024, 0, stream>>>(ws, out);
}